// Round 1
// baseline (655.409 us; speedup 1.0000x reference)
//
#include <hip/hip_runtime.h>
#include <hip/hip_bf16.h>
#include <stdint.h>

// Problem constants
#define E_NUM 8
#define D_DIM 512
#define H_DIM 2048
#define NTOK 16384   // B*S = 8*2048

typedef __bf16 bf16;
typedef __bf16 bf16x8 __attribute__((ext_vector_type(8)));
typedef __bf16 bf16x4 __attribute__((ext_vector_type(4)));
typedef float  f32x4  __attribute__((ext_vector_type(4)));

// GEMM tiling (m97-style)
#define BM 128
#define BN 128
#define BK 64
#define LDT 72   // BK + 8 pad elems: row stride 144B -> bank stride 4 -> 2-way (free)

// Workspace layout (bytes)
static const size_t OFF_CNT  = 0;            // 8 ints
static const size_t OFF_FILL = 32;           // 8 ints
static const size_t OFF_RB   = 64;           // 9 ints (row bases, 128-aligned cumsum)
static const size_t OFF_LIST = 128;          // E*NTOK ints = 512KB
static const size_t OFF_W1T  = 1ull << 20;                         // bf16 [E][H][D]
static const size_t OFF_W2T  = OFF_W1T + (size_t)E_NUM*H_DIM*D_DIM*2; // bf16 [E][D][H]
static const size_t OFF_HBUF = OFF_W2T + (size_t)E_NUM*H_DIM*D_DIM*2; // bf16 [<=33784][H]

// ---------------- routing ----------------
__global__ void count_kernel(const int* __restrict__ assign, int* __restrict__ cnt) {
  int n = blockIdx.x * blockDim.x + threadIdx.x;
  if (n >= NTOK) return;
  int e0 = assign[2*n], e1 = assign[2*n+1];
  atomicAdd(&cnt[e0], 1);
  if (e1 != e0) atomicAdd(&cnt[e1], 1);
}

__global__ void offsets_kernel(const int* __restrict__ cnt, int* __restrict__ rowbase) {
  if (threadIdx.x == 0) {
    int acc = 0;
    for (int e = 0; e < E_NUM; e++) {
      rowbase[e] = acc;
      acc += (cnt[e] + BM - 1) / BM * BM;   // pad each expert region to BM rows
    }
    rowbase[E_NUM] = acc;
  }
}

__global__ void fill_kernel(const int* __restrict__ assign, int* __restrict__ fill,
                            int* __restrict__ lists) {
  int n = blockIdx.x * blockDim.x + threadIdx.x;
  if (n >= NTOK) return;
  int e0 = assign[2*n], e1 = assign[2*n+1];
  int p0 = atomicAdd(&fill[e0], 1);
  lists[e0 * NTOK + p0] = n;
  if (e1 != e0) {
    int p1 = atomicAdd(&fill[e1], 1);
    lists[e1 * NTOK + p1] = n;
  }
}

// ---------------- weight transpose + cvt: [E][R][C] f32 -> [E][C][R] bf16 ----------------
__global__ void transpose_cvt(const float* __restrict__ in, bf16* __restrict__ out,
                              int R, int C) {
  __shared__ float tile[32][33];
  int e = blockIdx.z;
  int c0 = blockIdx.x * 32, r0 = blockIdx.y * 32;
  const float* src = in + (size_t)e * R * C;
  bf16* dst = out + (size_t)e * R * C;
  int tx = threadIdx.x, ty = threadIdx.y;  // 32 x 8
  #pragma unroll
  for (int i = 0; i < 32; i += 8)
    tile[ty + i][tx] = src[(size_t)(r0 + ty + i) * C + c0 + tx];
  __syncthreads();
  #pragma unroll
  for (int i = 0; i < 32; i += 8)
    dst[(size_t)(c0 + ty + i) * R + r0 + tx] = (bf16)tile[tx][ty + i];
}

// ---------------- GEMM1: h = relu(Xg @ W1 + b1), bf16 out to hbuf ----------------
__global__ __launch_bounds__(256) void gemm1(
    const float* __restrict__ x, const bf16* __restrict__ w1t,
    const float* __restrict__ b1, const int* __restrict__ lists,
    const int* __restrict__ cnt, const int* __restrict__ rowbase,
    bf16* __restrict__ hbuf) {
  int e = blockIdx.z;
  int ce = cnt[e];
  int m0 = blockIdx.y * BM;
  if (m0 >= ce) return;
  int n0 = blockIdx.x * BN;

  __shared__ bf16 xs[BM][LDT];
  __shared__ bf16 bs[BN][LDT];
  __shared__ int tok[BM];

  int tid = threadIdx.x;
  if (tid < BM) {
    int r = m0 + tid;
    tok[tid] = (r < ce) ? lists[e * NTOK + r] : lists[e * NTOK];  // clamp to a valid token
  }
  __syncthreads();

  const bf16* w1e = w1t + (size_t)e * H_DIM * D_DIM;
  int wave = tid >> 6, lane = tid & 63;
  int quad = lane >> 4, l16 = lane & 15;
  int wm = (wave & 1) * 64, wn = (wave >> 1) * 64;
  f32x4 acc[4][4] = {};

  for (int k0 = 0; k0 < D_DIM; k0 += BK) {
    // stage A: 128 rows x 64 f32 -> bf16. unit = float4, 16 units/row, 8/thread
    #pragma unroll
    for (int i = 0; i < 8; i++) {
      int idx = tid + i * 256;
      int r = idx >> 4, u = idx & 15;
      const float4 v = *reinterpret_cast<const float4*>(x + (size_t)tok[r] * D_DIM + k0 + u * 4);
      bf16x4 b; b[0] = (bf16)v.x; b[1] = (bf16)v.y; b[2] = (bf16)v.z; b[3] = (bf16)v.w;
      *reinterpret_cast<bf16x4*>(&xs[r][u * 4]) = b;
    }
    // stage B^T: 128 rows x 64 bf16. unit = 16B (8 bf16), 8 units/row, 4/thread
    #pragma unroll
    for (int i = 0; i < 4; i++) {
      int idx = tid + i * 256;
      int r = idx >> 3, u = idx & 7;
      *reinterpret_cast<uint4*>(&bs[r][u * 8]) =
          *reinterpret_cast<const uint4*>(w1e + (size_t)(n0 + r) * D_DIM + k0 + u * 8);
    }
    __syncthreads();
    #pragma unroll
    for (int kk = 0; kk < BK; kk += 32) {
      bf16x8 af[4], bfr[4];
      #pragma unroll
      for (int i = 0; i < 4; i++)
        af[i] = *reinterpret_cast<const bf16x8*>(&xs[wm + i * 16 + l16][kk + quad * 8]);
      #pragma unroll
      for (int j = 0; j < 4; j++)
        bfr[j] = *reinterpret_cast<const bf16x8*>(&bs[wn + j * 16 + l16][kk + quad * 8]);
      #pragma unroll
      for (int i = 0; i < 4; i++)
        #pragma unroll
        for (int j = 0; j < 4; j++)
          acc[i][j] = __builtin_amdgcn_mfma_f32_16x16x32_bf16(af[i], bfr[j], acc[i][j], 0, 0, 0);
    }
    __syncthreads();
  }

  // epilogue: +b1, relu, cvt, store (padded rows are safe: per-expert regions are BM-aligned)
  bf16* hrow = hbuf + (size_t)(rowbase[e] + m0) * H_DIM;
  #pragma unroll
  for (int i = 0; i < 4; i++) {
    int row = wm + i * 16 + quad * 4;
    #pragma unroll
    for (int j = 0; j < 4; j++) {
      int col = n0 + wn + j * 16 + l16;
      float bias = b1[e * H_DIM + col];
      #pragma unroll
      for (int r = 0; r < 4; r++) {
        float v = acc[i][j][r] + bias;
        v = v > 0.f ? v : 0.f;
        hrow[(size_t)(row + r) * H_DIM + col] = (bf16)v;
      }
    }
  }
}

// ---------------- GEMM2: out += 0.5*(h @ W2 + b2), scattered fp32 atomicAdd ----------------
__global__ __launch_bounds__(256) void gemm2(
    const bf16* __restrict__ hbuf, const bf16* __restrict__ w2t,
    const float* __restrict__ b2, const int* __restrict__ lists,
    const int* __restrict__ cnt, const int* __restrict__ rowbase,
    float* __restrict__ out) {
  int e = blockIdx.z;
  int ce = cnt[e];
  int m0 = blockIdx.y * BM;
  if (m0 >= ce) return;
  int n0 = blockIdx.x * BN;   // 4 chunks over D=512

  __shared__ bf16 hs[BM][LDT];
  __shared__ bf16 bs[BN][LDT];
  __shared__ int tok[BM];

  int tid = threadIdx.x;
  if (tid < BM) {
    int r = m0 + tid;
    tok[tid] = (r < ce) ? lists[e * NTOK + r] : -1;
  }
  __syncthreads();

  const bf16* hbase = hbuf + (size_t)(rowbase[e] + m0) * H_DIM;
  const bf16* w2e = w2t + (size_t)e * H_DIM * D_DIM;
  int wave = tid >> 6, lane = tid & 63;
  int quad = lane >> 4, l16 = lane & 15;
  int wm = (wave & 1) * 64, wn = (wave >> 1) * 64;
  f32x4 acc[4][4] = {};

  for (int k0 = 0; k0 < H_DIM; k0 += BK) {
    #pragma unroll
    for (int i = 0; i < 4; i++) {
      int idx = tid + i * 256;
      int r = idx >> 3, u = idx & 7;
      *reinterpret_cast<uint4*>(&hs[r][u * 8]) =
          *reinterpret_cast<const uint4*>(hbase + (size_t)r * H_DIM + k0 + u * 8);
    }
    #pragma unroll
    for (int i = 0; i < 4; i++) {
      int idx = tid + i * 256;
      int r = idx >> 3, u = idx & 7;
      *reinterpret_cast<uint4*>(&bs[r][u * 8]) =
          *reinterpret_cast<const uint4*>(w2e + (size_t)(n0 + r) * H_DIM + k0 + u * 8);
    }
    __syncthreads();
    #pragma unroll
    for (int kk = 0; kk < BK; kk += 32) {
      bf16x8 af[4], bfr[4];
      #pragma unroll
      for (int i = 0; i < 4; i++)
        af[i] = *reinterpret_cast<const bf16x8*>(&hs[wm + i * 16 + l16][kk + quad * 8]);
      #pragma unroll
      for (int j = 0; j < 4; j++)
        bfr[j] = *reinterpret_cast<const bf16x8*>(&bs[wn + j * 16 + l16][kk + quad * 8]);
      #pragma unroll
      for (int i = 0; i < 4; i++)
        #pragma unroll
        for (int j = 0; j < 4; j++)
          acc[i][j] = __builtin_amdgcn_mfma_f32_16x16x32_bf16(af[i], bfr[j], acc[i][j], 0, 0, 0);
    }
    __syncthreads();
  }

  #pragma unroll
  for (int i = 0; i < 4; i++) {
    int row = wm + i * 16 + quad * 4;
    #pragma unroll
    for (int j = 0; j < 4; j++) {
      int col = n0 + wn + j * 16 + l16;
      float bias = b2[e * D_DIM + col];
      #pragma unroll
      for (int r = 0; r < 4; r++) {
        int t = tok[row + r];
        if (t >= 0) {
          float v = 0.5f * (acc[i][j][r] + bias);
          atomicAdd(&out[(size_t)t * D_DIM + col], v);
        }
      }
    }
  }
}

// ---------------- launch ----------------
extern "C" void kernel_launch(void* const* d_in, const int* in_sizes, int n_in,
                              void* d_out, int out_size, void* d_ws, size_t ws_size,
                              hipStream_t stream) {
  const float* x      = (const float*)d_in[0];
  const int*   assign = (const int*)d_in[1];
  const float* W1     = (const float*)d_in[2];
  const float* b1     = (const float*)d_in[3];
  const float* W2     = (const float*)d_in[4];
  const float* b2     = (const float*)d_in[5];
  float* out = (float*)d_out;
  char* ws = (char*)d_ws;

  int* cnt     = (int*)(ws + OFF_CNT);
  int* fill    = (int*)(ws + OFF_FILL);
  int* rowbase = (int*)(ws + OFF_RB);
  int* lists   = (int*)(ws + OFF_LIST);
  bf16* w1t    = (bf16*)(ws + OFF_W1T);
  bf16* w2t    = (bf16*)(ws + OFF_W2T);
  bf16* hbuf   = (bf16*)(ws + OFF_HBUF);

  hipMemsetAsync(ws, 0, 128, stream);                         // cnt/fill/rowbase
  hipMemsetAsync(d_out, 0, (size_t)out_size * sizeof(float), stream);

  count_kernel<<<NTOK / 256, 256, 0, stream>>>(assign, cnt);
  offsets_kernel<<<1, 64, 0, stream>>>(cnt, rowbase);
  fill_kernel<<<NTOK / 256, 256, 0, stream>>>(assign, fill, lists);

  // W1 [E][D][H] -> W1T [E][H][D];  W2 [E][H][D] -> W2T [E][D][H]
  transpose_cvt<<<dim3(H_DIM / 32, D_DIM / 32, E_NUM), dim3(32, 8), 0, stream>>>(W1, w1t, D_DIM, H_DIM);
  transpose_cvt<<<dim3(D_DIM / 32, H_DIM / 32, E_NUM), dim3(32, 8), 0, stream>>>(W2, w2t, H_DIM, D_DIM);

  gemm1<<<dim3(H_DIM / BN, NTOK / BM, E_NUM), 256, 0, stream>>>(x, w1t, b1, lists, cnt, rowbase, hbuf);
  gemm2<<<dim3(D_DIM / BN, NTOK / BM, E_NUM), 256, 0, stream>>>(hbuf, w2t, b2, lists, cnt, rowbase, out);

  (void)in_sizes; (void)n_in; (void)ws_size;
}

// Round 2
// 653.232 us; speedup vs baseline: 1.0033x; 1.0033x over previous
//
#include <hip/hip_runtime.h>
#include <hip/hip_bf16.h>
#include <stdint.h>

// Problem constants
#define E_NUM 8
#define D_DIM 512
#define H_DIM 2048
#define NTOK 16384   // B*S = 8*2048

typedef __bf16 bf16;
typedef __bf16 bf16x8 __attribute__((ext_vector_type(8)));
typedef __bf16 bf16x4 __attribute__((ext_vector_type(4)));
typedef float  f32x4  __attribute__((ext_vector_type(4)));

// GEMM tiling (m97-style): 128x128 tile, BK=64, UNPADDED LDS (required by global_load_lds)
#define BM 128
#define BN 128
#define BK 64

// async global->LDS, 16B per lane (m97 rung)
typedef __attribute__((address_space(1))) const void* gas_cp;
typedef __attribute__((address_space(3))) void* las_p;
__device__ __forceinline__ void gl_lds16(const void* g, void* l) {
  __builtin_amdgcn_global_load_lds((gas_cp)g, (las_p)l, 16, 0, 0);
}

// Workspace layout (bytes)
static const size_t OFF_CNT  = 0;            // 8 ints
static const size_t OFF_FILL = 32;           // 8 ints
static const size_t OFF_RB   = 64;           // 9 ints (row bases, 128-aligned cumsum)
static const size_t OFF_LIST = 128;          // E*NTOK ints = 512KB
static const size_t OFF_XBF  = 1ull << 20;                              // bf16 [NTOK][D] = 16.8MB
static const size_t OFF_W1T  = OFF_XBF + (size_t)NTOK*D_DIM*2;          // bf16 [E][H][D]
static const size_t OFF_W2T  = OFF_W1T + (size_t)E_NUM*H_DIM*D_DIM*2;   // bf16 [E][D][H]
static const size_t OFF_HBUF = OFF_W2T + (size_t)E_NUM*H_DIM*D_DIM*2;   // bf16 [<=33784][H]

// ---------------- routing ----------------
__global__ void count_kernel(const int* __restrict__ assign, int* __restrict__ cnt) {
  int n = blockIdx.x * blockDim.x + threadIdx.x;
  if (n >= NTOK) return;
  int e0 = assign[2*n], e1 = assign[2*n+1];
  atomicAdd(&cnt[e0], 1);
  if (e1 != e0) atomicAdd(&cnt[e1], 1);
}

__global__ void offsets_kernel(const int* __restrict__ cnt, int* __restrict__ rowbase) {
  if (threadIdx.x == 0) {
    int acc = 0;
    for (int e = 0; e < E_NUM; e++) {
      rowbase[e] = acc;
      acc += (cnt[e] + BM - 1) / BM * BM;
    }
    rowbase[E_NUM] = acc;
  }
}

__global__ void fill_kernel(const int* __restrict__ assign, int* __restrict__ fill,
                            int* __restrict__ lists) {
  int n = blockIdx.x * blockDim.x + threadIdx.x;
  if (n >= NTOK) return;
  int e0 = assign[2*n], e1 = assign[2*n+1];
  int p0 = atomicAdd(&fill[e0], 1);
  lists[e0 * NTOK + p0] = n;
  if (e1 != e0) {
    int p1 = atomicAdd(&fill[e1], 1);
    lists[e1 * NTOK + p1] = n;
  }
}

// ---------------- x f32 -> bf16 (un-gathered, one pass) ----------------
__global__ void cvt_x(const float* __restrict__ x, bf16* __restrict__ xbf) {
  size_t i = ((size_t)blockIdx.x * 256 + threadIdx.x) * 8;
  float4 a = *reinterpret_cast<const float4*>(x + i);
  float4 b = *reinterpret_cast<const float4*>(x + i + 4);
  bf16x8 o;
  o[0] = (bf16)a.x; o[1] = (bf16)a.y; o[2] = (bf16)a.z; o[3] = (bf16)a.w;
  o[4] = (bf16)b.x; o[5] = (bf16)b.y; o[6] = (bf16)b.z; o[7] = (bf16)b.w;
  *reinterpret_cast<bf16x8*>(xbf + i) = o;
}

// ---------------- weight transpose + cvt: [E][R][C] f32 -> [E][C][R] bf16 ----------------
__global__ void transpose_cvt(const float* __restrict__ in, bf16* __restrict__ out,
                              int R, int C) {
  __shared__ float tile[32][33];
  int e = blockIdx.z;
  int c0 = blockIdx.x * 32, r0 = blockIdx.y * 32;
  const float* src = in + (size_t)e * R * C;
  bf16* dst = out + (size_t)e * R * C;
  int tx = threadIdx.x, ty = threadIdx.y;  // 32 x 8
  #pragma unroll
  for (int i = 0; i < 32; i += 8)
    tile[ty + i][tx] = src[(size_t)(r0 + ty + i) * C + c0 + tx];
  __syncthreads();
  #pragma unroll
  for (int i = 0; i < 32; i += 8)
    dst[(size_t)(c0 + ty + i) * R + r0 + tx] = (bf16)tile[tx][ty + i];
}

// ---------------- GEMM1: h = relu(Xg @ W1 + b1), bf16 out to hbuf ----------------
// A gathered from xbf via per-lane addresses; staging via global_load_lds x16B.
__global__ __launch_bounds__(256) void gemm1(
    const bf16* __restrict__ xbf, const bf16* __restrict__ w1t,
    const float* __restrict__ b1, const int* __restrict__ lists,
    const int* __restrict__ cnt, const int* __restrict__ rowbase,
    bf16* __restrict__ hbuf) {
  int e = blockIdx.z;
  int ce = cnt[e];
  int m0 = blockIdx.y * BM;
  if (m0 >= ce) return;
  int n0 = blockIdx.x * BN;

  __shared__ bf16 xs[BM * BK];   // [row][k], stride 64
  __shared__ bf16 bs[BN * BK];
  __shared__ int tok[BM];

  int tid = threadIdx.x;
  if (tid < BM) {
    int r = m0 + tid;
    tok[tid] = (r < ce) ? lists[e * NTOK + r] : lists[e * NTOK];  // clamp: padded rows compute garbage, skipped later
  }
  __syncthreads();

  const bf16* w1e = w1t + (size_t)e * H_DIM * D_DIM + (size_t)n0 * D_DIM;
  int wave = tid >> 6, lane = tid & 63;
  int quad = lane >> 4, l16 = lane & 15;
  int lr = lane >> 3, lc = (lane & 7) * 8;   // staging: 8 rows x 64 cols per wave-instr
  int wm = (wave & 1) * 64, wn = (wave >> 1) * 64;
  f32x4 acc[4][4] = {};

  for (int k0 = 0; k0 < D_DIM; k0 += BK) {
    #pragma unroll
    for (int i = 0; i < 4; i++) {
      int s = wave * 4 + i;                 // segment: rows [8s, 8s+8)
      int t = tok[s * 8 + lr];
      gl_lds16(xbf + (size_t)t * D_DIM + k0 + lc, &xs[s * 512]);
    }
    #pragma unroll
    for (int i = 0; i < 4; i++) {
      int s = wave * 4 + i;
      gl_lds16(w1e + (size_t)(s * 8 + lr) * D_DIM + k0 + lc, &bs[s * 512]);
    }
    __syncthreads();
    #pragma unroll
    for (int kk = 0; kk < BK; kk += 32) {
      bf16x8 af[4], bfr[4];
      #pragma unroll
      for (int i = 0; i < 4; i++)
        af[i] = *reinterpret_cast<const bf16x8*>(&xs[(wm + i * 16 + l16) * BK + kk + quad * 8]);
      #pragma unroll
      for (int j = 0; j < 4; j++)
        bfr[j] = *reinterpret_cast<const bf16x8*>(&bs[(wn + j * 16 + l16) * BK + kk + quad * 8]);
      #pragma unroll
      for (int i = 0; i < 4; i++)
        #pragma unroll
        for (int j = 0; j < 4; j++)
          acc[i][j] = __builtin_amdgcn_mfma_f32_16x16x32_bf16(af[i], bfr[j], acc[i][j], 0, 0, 0);
    }
    __syncthreads();
  }

  bf16* hrow = hbuf + (size_t)(rowbase[e] + m0) * H_DIM;
  #pragma unroll
  for (int i = 0; i < 4; i++) {
    int row = wm + i * 16 + quad * 4;
    #pragma unroll
    for (int j = 0; j < 4; j++) {
      int col = n0 + wn + j * 16 + l16;
      float bias = b1[e * H_DIM + col];
      #pragma unroll
      for (int r = 0; r < 4; r++) {
        float v = acc[i][j][r] + bias;
        v = v > 0.f ? v : 0.f;
        hrow[(size_t)(row + r) * H_DIM + col] = (bf16)v;
      }
    }
  }
}

// ---------------- GEMM2: out += 0.5*(h @ W2 + b2), scattered fp32 atomicAdd ----------------
__global__ __launch_bounds__(256) void gemm2(
    const bf16* __restrict__ hbuf, const bf16* __restrict__ w2t,
    const float* __restrict__ b2, const int* __restrict__ lists,
    const int* __restrict__ cnt, const int* __restrict__ rowbase,
    float* __restrict__ out) {
  int e = blockIdx.z;
  int ce = cnt[e];
  int m0 = blockIdx.y * BM;
  if (m0 >= ce) return;
  int n0 = blockIdx.x * BN;   // 4 chunks over D=512

  __shared__ bf16 hs[BM * BK];
  __shared__ bf16 bs[BN * BK];
  __shared__ int tok[BM];

  int tid = threadIdx.x;
  if (tid < BM) {
    int r = m0 + tid;
    tok[tid] = (r < ce) ? lists[e * NTOK + r] : -1;
  }
  __syncthreads();

  const bf16* hbase = hbuf + (size_t)(rowbase[e] + m0) * H_DIM;
  const bf16* w2e = w2t + (size_t)e * H_DIM * D_DIM + (size_t)n0 * H_DIM;
  int wave = tid >> 6, lane = tid & 63;
  int quad = lane >> 4, l16 = lane & 15;
  int lr = lane >> 3, lc = (lane & 7) * 8;
  int wm = (wave & 1) * 64, wn = (wave >> 1) * 64;
  f32x4 acc[4][4] = {};

  for (int k0 = 0; k0 < H_DIM; k0 += BK) {
    #pragma unroll
    for (int i = 0; i < 4; i++) {
      int s = wave * 4 + i;
      gl_lds16(hbase + (size_t)(s * 8 + lr) * H_DIM + k0 + lc, &hs[s * 512]);
    }
    #pragma unroll
    for (int i = 0; i < 4; i++) {
      int s = wave * 4 + i;
      gl_lds16(w2e + (size_t)(s * 8 + lr) * H_DIM + k0 + lc, &bs[s * 512]);
    }
    __syncthreads();
    #pragma unroll
    for (int kk = 0; kk < BK; kk += 32) {
      bf16x8 af[4], bfr[4];
      #pragma unroll
      for (int i = 0; i < 4; i++)
        af[i] = *reinterpret_cast<const bf16x8*>(&hs[(wm + i * 16 + l16) * BK + kk + quad * 8]);
      #pragma unroll
      for (int j = 0; j < 4; j++)
        bfr[j] = *reinterpret_cast<const bf16x8*>(&bs[(wn + j * 16 + l16) * BK + kk + quad * 8]);
      #pragma unroll
      for (int i = 0; i < 4; i++)
        #pragma unroll
        for (int j = 0; j < 4; j++)
          acc[i][j] = __builtin_amdgcn_mfma_f32_16x16x32_bf16(af[i], bfr[j], acc[i][j], 0, 0, 0);
    }
    __syncthreads();
  }

  #pragma unroll
  for (int i = 0; i < 4; i++) {
    int row = wm + i * 16 + quad * 4;
    #pragma unroll
    for (int j = 0; j < 4; j++) {
      int col = n0 + wn + j * 16 + l16;
      float bias = b2[e * D_DIM + col];
      #pragma unroll
      for (int r = 0; r < 4; r++) {
        int t = tok[row + r];
        if (t >= 0) {
          float v = 0.5f * (acc[i][j][r] + bias);
          atomicAdd(&out[(size_t)t * D_DIM + col], v);
        }
      }
    }
  }
}

// ---------------- launch ----------------
extern "C" void kernel_launch(void* const* d_in, const int* in_sizes, int n_in,
                              void* d_out, int out_size, void* d_ws, size_t ws_size,
                              hipStream_t stream) {
  const float* x      = (const float*)d_in[0];
  const int*   assign = (const int*)d_in[1];
  const float* W1     = (const float*)d_in[2];
  const float* b1     = (const float*)d_in[3];
  const float* W2     = (const float*)d_in[4];
  const float* b2     = (const float*)d_in[5];
  float* out = (float*)d_out;
  char* ws = (char*)d_ws;

  int* cnt     = (int*)(ws + OFF_CNT);
  int* fill    = (int*)(ws + OFF_FILL);
  int* rowbase = (int*)(ws + OFF_RB);
  int* lists   = (int*)(ws + OFF_LIST);
  bf16* xbf    = (bf16*)(ws + OFF_XBF);
  bf16* w1t    = (bf16*)(ws + OFF_W1T);
  bf16* w2t    = (bf16*)(ws + OFF_W2T);
  bf16* hbuf   = (bf16*)(ws + OFF_HBUF);

  hipMemsetAsync(ws, 0, 128, stream);
  hipMemsetAsync(d_out, 0, (size_t)out_size * sizeof(float), stream);

  count_kernel<<<NTOK / 256, 256, 0, stream>>>(assign, cnt);
  offsets_kernel<<<1, 64, 0, stream>>>(cnt, rowbase);
  fill_kernel<<<NTOK / 256, 256, 0, stream>>>(assign, fill, lists);

  cvt_x<<<(NTOK * D_DIM) / (256 * 8), 256, 0, stream>>>(x, xbf);
  // W1 [E][D][H] -> W1T [E][H][D];  W2 [E][H][D] -> W2T [E][D][H]
  transpose_cvt<<<dim3(H_DIM / 32, D_DIM / 32, E_NUM), dim3(32, 8), 0, stream>>>(W1, w1t, D_DIM, H_DIM);
  transpose_cvt<<<dim3(D_DIM / 32, H_DIM / 32, E_NUM), dim3(32, 8), 0, stream>>>(W2, w2t, H_DIM, D_DIM);

  gemm1<<<dim3(H_DIM / BN, NTOK / BM, E_NUM), 256, 0, stream>>>(xbf, w1t, b1, lists, cnt, rowbase, hbuf);
  gemm2<<<dim3(D_DIM / BN, NTOK / BM, E_NUM), 256, 0, stream>>>(hbuf, w2t, b2, lists, cnt, rowbase, out);

  (void)in_sizes; (void)n_in; (void)ws_size;
}

// Round 3
// 562.357 us; speedup vs baseline: 1.1655x; 1.1616x over previous
//
#include <hip/hip_runtime.h>
#include <hip/hip_bf16.h>
#include <stdint.h>

// Problem constants
#define E_NUM 8
#define D_DIM 512
#define H_DIM 2048
#define NTOK 16384   // B*S = 8*2048

typedef __bf16 bf16;
typedef __bf16 bf16x8 __attribute__((ext_vector_type(8)));
typedef float  f32x4  __attribute__((ext_vector_type(4)));

// GEMM tiling: 128x128 tile, BK=64, UNPADDED LDS (required by global_load_lds),
// double-buffered (m99 pattern — pays here because occupancy ~2 blocks/CU => no implicit overlap)
#define BM 128
#define BN 128
#define BK 64

// async global->LDS, 16B per lane
typedef __attribute__((address_space(1))) const void* gas_cp;
typedef __attribute__((address_space(3))) void* las_p;
__device__ __forceinline__ void gl_lds16(const void* g, void* l) {
  __builtin_amdgcn_global_load_lds((gas_cp)g, (las_p)l, 16, 0, 0);
}

// Workspace layout (bytes)
static const size_t OFF_FILL = 32;           // 8 ints (doubles as per-expert count after fill)
static const size_t OFF_RB   = 64;           // 9 ints (row bases, 128-aligned cumsum)
static const size_t OFF_LIST = 128;          // E*NTOK ints = 512KB
static const size_t OFF_XBF  = 1ull << 20;                              // bf16 [NTOK][D] = 16.8MB
static const size_t OFF_W1T  = OFF_XBF + (size_t)NTOK*D_DIM*2;          // bf16 [E][H][D]
static const size_t OFF_W2T  = OFF_W1T + (size_t)E_NUM*H_DIM*D_DIM*2;   // bf16 [E][D][H]
static const size_t OFF_HBUF = OFF_W2T + (size_t)E_NUM*H_DIM*D_DIM*2;   // bf16 [<=33784][H]

// ---------------- routing: fill lists + counts in one kernel ----------------
__global__ void fill_kernel(const int* __restrict__ assign, int* __restrict__ fill,
                            int* __restrict__ lists) {
  int n = blockIdx.x * blockDim.x + threadIdx.x;
  if (n >= NTOK) return;
  int e0 = assign[2*n], e1 = assign[2*n+1];
  int p0 = atomicAdd(&fill[e0], 1);
  lists[e0 * NTOK + p0] = n;
  if (e1 != e0) {
    int p1 = atomicAdd(&fill[e1], 1);
    lists[e1 * NTOK + p1] = n;
  }
}

__global__ void offsets_kernel(const int* __restrict__ fill, int* __restrict__ rowbase) {
  if (threadIdx.x == 0) {
    int acc = 0;
    for (int e = 0; e < E_NUM; e++) {
      rowbase[e] = acc;
      acc += (fill[e] + BM - 1) / BM * BM;
    }
    rowbase[E_NUM] = acc;
  }
}

// ---------------- x f32 -> bf16 (un-gathered, one pass) ----------------
__global__ void cvt_x(const float* __restrict__ x, bf16* __restrict__ xbf) {
  size_t i = ((size_t)blockIdx.x * 256 + threadIdx.x) * 8;
  float4 a = *reinterpret_cast<const float4*>(x + i);
  float4 b = *reinterpret_cast<const float4*>(x + i + 4);
  bf16x8 o;
  o[0] = (bf16)a.x; o[1] = (bf16)a.y; o[2] = (bf16)a.z; o[3] = (bf16)a.w;
  o[4] = (bf16)b.x; o[5] = (bf16)b.y; o[6] = (bf16)b.z; o[7] = (bf16)b.w;
  *reinterpret_cast<bf16x8*>(xbf + i) = o;
}

// ---------------- weight transpose + cvt: [E][R][C] f32 -> [E][C][R] bf16 ----------------
__global__ void transpose_cvt(const float* __restrict__ in, bf16* __restrict__ out,
                              int R, int C) {
  __shared__ float tile[32][33];
  int e = blockIdx.z;
  int c0 = blockIdx.x * 32, r0 = blockIdx.y * 32;
  const float* src = in + (size_t)e * R * C;
  bf16* dst = out + (size_t)e * R * C;
  int tx = threadIdx.x, ty = threadIdx.y;  // 32 x 8
  #pragma unroll
  for (int i = 0; i < 32; i += 8)
    tile[ty + i][tx] = src[(size_t)(r0 + ty + i) * C + c0 + tx];
  __syncthreads();
  #pragma unroll
  for (int i = 0; i < 32; i += 8)
    dst[(size_t)(c0 + ty + i) * R + r0 + tx] = (bf16)tile[tx][ty + i];
}

// ---------------- GEMM1: h = relu(Xg @ W1 + b1), bf16 out to hbuf ----------------
__global__ __launch_bounds__(256) void gemm1(
    const bf16* __restrict__ xbf, const bf16* __restrict__ w1t,
    const float* __restrict__ b1, const int* __restrict__ lists,
    const int* __restrict__ cnt, const int* __restrict__ rowbase,
    bf16* __restrict__ hbuf) {
  int e = blockIdx.z;
  int ce = cnt[e];
  int m0 = blockIdx.y * BM;
  if (m0 >= ce) return;
  int n0 = blockIdx.x * BN;

  __shared__ bf16 xs[2][BM * BK];   // [row][k], stride 64, double-buffered
  __shared__ bf16 bs[2][BN * BK];
  __shared__ int tok[BM];

  int tid = threadIdx.x;
  if (tid < BM) {
    int r = m0 + tid;
    tok[tid] = (r < ce) ? lists[e * NTOK + r] : lists[e * NTOK];
  }
  __syncthreads();

  const bf16* w1e = w1t + (size_t)e * H_DIM * D_DIM + (size_t)n0 * D_DIM;
  int wave = tid >> 6, lane = tid & 63;
  int quad = lane >> 4, l16 = lane & 15;
  int lr = lane >> 3, lc = (lane & 7) * 8;   // staging: 8 rows x 64 cols per wave-instr
  int wm = (wave & 1) * 64, wn = (wave >> 1) * 64;
  f32x4 acc[4][4] = {};

  auto stage = [&](int buf, int k0) {
    #pragma unroll
    for (int i = 0; i < 4; i++) {
      int s = wave * 4 + i;                 // segment: rows [8s, 8s+8)
      int t = tok[s * 8 + lr];
      gl_lds16(xbf + (size_t)t * D_DIM + k0 + lc, &xs[buf][s * 512]);
    }
    #pragma unroll
    for (int i = 0; i < 4; i++) {
      int s = wave * 4 + i;
      gl_lds16(w1e + (size_t)(s * 8 + lr) * D_DIM + k0 + lc, &bs[buf][s * 512]);
    }
  };

  const int nk = D_DIM / BK;  // 8
  stage(0, 0);
  for (int ki = 0; ki < nk; ki++) {
    __syncthreads();                                       // drains buf[ki&1] loads
    if (ki + 1 < nk) stage((ki + 1) & 1, (ki + 1) * BK);   // fly during compute
    const bf16* xsc = xs[ki & 1];
    const bf16* bsc = bs[ki & 1];
    #pragma unroll
    for (int kk = 0; kk < BK; kk += 32) {
      bf16x8 af[4], bfr[4];
      #pragma unroll
      for (int i = 0; i < 4; i++)
        af[i] = *reinterpret_cast<const bf16x8*>(&xsc[(wm + i * 16 + l16) * BK + kk + quad * 8]);
      #pragma unroll
      for (int j = 0; j < 4; j++)
        bfr[j] = *reinterpret_cast<const bf16x8*>(&bsc[(wn + j * 16 + l16) * BK + kk + quad * 8]);
      #pragma unroll
      for (int i = 0; i < 4; i++)
        #pragma unroll
        for (int j = 0; j < 4; j++)
          acc[i][j] = __builtin_amdgcn_mfma_f32_16x16x32_bf16(af[i], bfr[j], acc[i][j], 0, 0, 0);
    }
  }

  bf16* hrow = hbuf + (size_t)(rowbase[e] + m0) * H_DIM;
  #pragma unroll
  for (int i = 0; i < 4; i++) {
    int row = wm + i * 16 + quad * 4;
    #pragma unroll
    for (int j = 0; j < 4; j++) {
      int col = n0 + wn + j * 16 + l16;
      float bias = b1[e * H_DIM + col];
      #pragma unroll
      for (int r = 0; r < 4; r++) {
        float v = acc[i][j][r] + bias;
        v = v > 0.f ? v : 0.f;
        hrow[(size_t)(row + r) * H_DIM + col] = (bf16)v;
      }
    }
  }
}

// ---------------- GEMM2: out += 0.5*(h @ W2 + b2), scattered fp32 atomicAdd ----------------
__global__ __launch_bounds__(256) void gemm2(
    const bf16* __restrict__ hbuf, const bf16* __restrict__ w2t,
    const float* __restrict__ b2, const int* __restrict__ lists,
    const int* __restrict__ cnt, const int* __restrict__ rowbase,
    float* __restrict__ out) {
  int e = blockIdx.z;
  int ce = cnt[e];
  int m0 = blockIdx.y * BM;
  if (m0 >= ce) return;
  int n0 = blockIdx.x * BN;   // 4 chunks over D=512

  __shared__ bf16 hs[2][BM * BK];
  __shared__ bf16 bs[2][BN * BK];
  __shared__ int tok[BM];

  int tid = threadIdx.x;
  if (tid < BM) {
    int r = m0 + tid;
    tok[tid] = (r < ce) ? lists[e * NTOK + r] : -1;
  }
  __syncthreads();

  const bf16* hbase = hbuf + (size_t)(rowbase[e] + m0) * H_DIM;
  const bf16* w2e = w2t + (size_t)e * H_DIM * D_DIM + (size_t)n0 * H_DIM;
  int wave = tid >> 6, lane = tid & 63;
  int quad = lane >> 4, l16 = lane & 15;
  int lr = lane >> 3, lc = (lane & 7) * 8;
  int wm = (wave & 1) * 64, wn = (wave >> 1) * 64;
  f32x4 acc[4][4] = {};

  auto stage = [&](int buf, int k0) {
    #pragma unroll
    for (int i = 0; i < 4; i++) {
      int s = wave * 4 + i;
      gl_lds16(hbase + (size_t)(s * 8 + lr) * H_DIM + k0 + lc, &hs[buf][s * 512]);
    }
    #pragma unroll
    for (int i = 0; i < 4; i++) {
      int s = wave * 4 + i;
      gl_lds16(w2e + (size_t)(s * 8 + lr) * H_DIM + k0 + lc, &bs[buf][s * 512]);
    }
  };

  const int nk = H_DIM / BK;  // 32
  stage(0, 0);
  for (int ki = 0; ki < nk; ki++) {
    __syncthreads();
    if (ki + 1 < nk) stage((ki + 1) & 1, (ki + 1) * BK);
    const bf16* hsc = hs[ki & 1];
    const bf16* bsc = bs[ki & 1];
    #pragma unroll
    for (int kk = 0; kk < BK; kk += 32) {
      bf16x8 af[4], bfr[4];
      #pragma unroll
      for (int i = 0; i < 4; i++)
        af[i] = *reinterpret_cast<const bf16x8*>(&hsc[(wm + i * 16 + l16) * BK + kk + quad * 8]);
      #pragma unroll
      for (int j = 0; j < 4; j++)
        bfr[j] = *reinterpret_cast<const bf16x8*>(&bsc[(wn + j * 16 + l16) * BK + kk + quad * 8]);
      #pragma unroll
      for (int i = 0; i < 4; i++)
        #pragma unroll
        for (int j = 0; j < 4; j++)
          acc[i][j] = __builtin_amdgcn_mfma_f32_16x16x32_bf16(af[i], bfr[j], acc[i][j], 0, 0, 0);
    }
  }

  #pragma unroll
  for (int i = 0; i < 4; i++) {
    int row = wm + i * 16 + quad * 4;
    #pragma unroll
    for (int j = 0; j < 4; j++) {
      int col = n0 + wn + j * 16 + l16;
      float bias = b2[e * D_DIM + col];
      #pragma unroll
      for (int r = 0; r < 4; r++) {
        int t = tok[row + r];
        if (t >= 0) {
          float v = 0.5f * (acc[i][j][r] + bias);
          atomicAdd(&out[(size_t)t * D_DIM + col], v);
        }
      }
    }
  }
}

// ---------------- launch ----------------
extern "C" void kernel_launch(void* const* d_in, const int* in_sizes, int n_in,
                              void* d_out, int out_size, void* d_ws, size_t ws_size,
                              hipStream_t stream) {
  const float* x      = (const float*)d_in[0];
  const int*   assign = (const int*)d_in[1];
  const float* W1     = (const float*)d_in[2];
  const float* b1     = (const float*)d_in[3];
  const float* W2     = (const float*)d_in[4];
  const float* b2     = (const float*)d_in[5];
  float* out = (float*)d_out;
  char* ws = (char*)d_ws;

  int* fill    = (int*)(ws + OFF_FILL);
  int* rowbase = (int*)(ws + OFF_RB);
  int* lists   = (int*)(ws + OFF_LIST);
  bf16* xbf    = (bf16*)(ws + OFF_XBF);
  bf16* w1t    = (bf16*)(ws + OFF_W1T);
  bf16* w2t    = (bf16*)(ws + OFF_W2T);
  bf16* hbuf   = (bf16*)(ws + OFF_HBUF);

  hipMemsetAsync(ws, 0, 128, stream);
  hipMemsetAsync(d_out, 0, (size_t)out_size * sizeof(float), stream);

  fill_kernel<<<NTOK / 256, 256, 0, stream>>>(assign, fill, lists);
  offsets_kernel<<<1, 64, 0, stream>>>(fill, rowbase);

  cvt_x<<<(NTOK * D_DIM) / (256 * 8), 256, 0, stream>>>(x, xbf);
  // W1 [E][D][H] -> W1T [E][H][D];  W2 [E][H][D] -> W2T [E][D][H]
  transpose_cvt<<<dim3(H_DIM / 32, D_DIM / 32, E_NUM), dim3(32, 8), 0, stream>>>(W1, w1t, D_DIM, H_DIM);
  transpose_cvt<<<dim3(D_DIM / 32, H_DIM / 32, E_NUM), dim3(32, 8), 0, stream>>>(W2, w2t, H_DIM, D_DIM);

  gemm1<<<dim3(H_DIM / BN, NTOK / BM, E_NUM), 256, 0, stream>>>(xbf, w1t, b1, lists, fill, rowbase, hbuf);
  gemm2<<<dim3(D_DIM / BN, NTOK / BM, E_NUM), 256, 0, stream>>>(hbuf, w2t, b2, lists, fill, rowbase, out);

  (void)in_sizes; (void)n_in; (void)ws_size;
}

// Round 5
// 544.324 us; speedup vs baseline: 1.2041x; 1.0331x over previous
//
#include <hip/hip_runtime.h>
#include <hip/hip_bf16.h>
#include <stdint.h>

// Problem constants
#define E_NUM 8
#define D_DIM 512
#define H_DIM 2048
#define NTOK 16384   // B*S = 8*2048

typedef __bf16 bf16;
typedef __bf16 bf16x8 __attribute__((ext_vector_type(8)));
typedef float  f32x4  __attribute__((ext_vector_type(4)));

// GEMM tiling: 128x128 tile, BK=64, UNPADDED LDS (required by global_load_lds).
// gemm1: double-buffered (measured best, r3). gemm2: single-buffered (measured best, r2).
// Both use an XCD-aware swizzle: the N-chunks of one row-block share lin%8 -> same XCD L2.
#define BM 128
#define BN 128
#define BK 64

// async global->LDS, 16B per lane
typedef __attribute__((address_space(1))) const void* gas_cp;
typedef __attribute__((address_space(3))) void* las_p;
__device__ __forceinline__ void gl_lds16(const void* g, void* l) {
  __builtin_amdgcn_global_load_lds((gas_cp)g, (las_p)l, 16, 0, 0);
}

// Workspace layout (bytes)
static const size_t OFF_FILL = 32;           // 8 ints (per-expert count after fill)
static const size_t OFF_LIST = 128;          // E*NTOK ints = 512KB
static const size_t OFF_XBF  = 1ull << 20;                              // bf16 [NTOK][D] = 16.8MB
static const size_t OFF_W1T  = OFF_XBF + (size_t)NTOK*D_DIM*2;          // bf16 [E][H][D]
static const size_t OFF_W2T  = OFF_W1T + (size_t)E_NUM*H_DIM*D_DIM*2;   // bf16 [E][D][H]
static const size_t OFF_HBUF = OFF_W2T + (size_t)E_NUM*H_DIM*D_DIM*2;   // bf16 [<=33792][H]

// rowbase for expert e, computed from counts (all blocks agree; cnt final at kernel launch)
__device__ __forceinline__ int rowbase_of(const int* cnt, int e) {
  int acc = 0;
  for (int i = 0; i < e; i++) acc += (cnt[i] + BM - 1) & ~(BM - 1);
  return acc;
}

// ---------------- routing: fill lists + counts in one kernel ----------------
__global__ void fill_kernel(const int* __restrict__ assign, int* __restrict__ fill,
                            int* __restrict__ lists) {
  int n = blockIdx.x * blockDim.x + threadIdx.x;
  if (n >= NTOK) return;
  int e0 = assign[2*n], e1 = assign[2*n+1];
  int p0 = atomicAdd(&fill[e0], 1);
  lists[e0 * NTOK + p0] = n;
  if (e1 != e0) {
    int p1 = atomicAdd(&fill[e1], 1);
    lists[e1 * NTOK + p1] = n;
  }
}

// ---------------- x f32 -> bf16 (un-gathered, one pass) ----------------
__global__ void cvt_x(const float* __restrict__ x, bf16* __restrict__ xbf) {
  size_t i = ((size_t)blockIdx.x * 256 + threadIdx.x) * 8;
  float4 a = *reinterpret_cast<const float4*>(x + i);
  float4 b = *reinterpret_cast<const float4*>(x + i + 4);
  bf16x8 o;
  o[0] = (bf16)a.x; o[1] = (bf16)a.y; o[2] = (bf16)a.z; o[3] = (bf16)a.w;
  o[4] = (bf16)b.x; o[5] = (bf16)b.y; o[6] = (bf16)b.z; o[7] = (bf16)b.w;
  *reinterpret_cast<bf16x8*>(xbf + i) = o;
}

// ---------------- weight transpose + cvt: [E][R][C] f32 -> [E][C][R] bf16 ----------------
__global__ void transpose_cvt(const float* __restrict__ in, bf16* __restrict__ out,
                              int R, int C) {
  __shared__ float tile[32][33];
  int e = blockIdx.z;
  int c0 = blockIdx.x * 32, r0 = blockIdx.y * 32;
  const float* src = in + (size_t)e * R * C;
  bf16* dst = out + (size_t)e * R * C;
  int tx = threadIdx.x, ty = threadIdx.y;  // 32 x 8
  #pragma unroll
  for (int i = 0; i < 32; i += 8)
    tile[ty + i][tx] = src[(size_t)(r0 + ty + i) * C + c0 + tx];
  __syncthreads();
  #pragma unroll
  for (int i = 0; i < 32; i += 8)
    dst[(size_t)(c0 + ty + i) * R + r0 + tx] = (bf16)tile[tx][ty + i];
}

// ---------------- GEMM1: h = relu(Xg @ W1 + b1), bf16 out to hbuf ----------------
// grid: 1D, lin = xcd + 8*(nc + NC1*rbHi); rb = rbHi*8 + xcd; NC1 = 16 chunks over H
#define NC1 (H_DIM / BN)   // 16
__global__ __launch_bounds__(256) void gemm1(
    const bf16* __restrict__ xbf, const bf16* __restrict__ w1t,
    const float* __restrict__ b1, const int* __restrict__ lists,
    const int* __restrict__ cnt, bf16* __restrict__ hbuf) {
  int lin = blockIdx.x;
  int xcd = lin & 7;
  int rem = lin >> 3;
  int nc  = rem & (NC1 - 1);
  int rb  = (rem >> 4) * 8 + xcd;          // rem>>log2(NC1)
  int e   = rb >> 7;                        // rb / 128
  int m0  = (rb & 127) * BM;
  int ce  = cnt[e];
  if (m0 >= ce) return;
  int n0 = nc * BN;
  int rbase = rowbase_of(cnt, e);

  __shared__ bf16 xs[2][BM * BK];   // [row][k], stride 64, double-buffered
  __shared__ bf16 bs[2][BN * BK];
  __shared__ int tok[BM];

  int tid = threadIdx.x;
  if (tid < BM) {
    int r = m0 + tid;
    tok[tid] = (r < ce) ? lists[e * NTOK + r] : lists[e * NTOK];
  }
  __syncthreads();

  const bf16* w1e = w1t + (size_t)e * H_DIM * D_DIM + (size_t)n0 * D_DIM;
  int wave = tid >> 6, lane = tid & 63;
  int quad = lane >> 4, l16 = lane & 15;
  int lr = lane >> 3, lc = (lane & 7) * 8;   // staging: 8 rows x 64 cols per wave-instr
  int wm = (wave & 1) * 64, wn = (wave >> 1) * 64;
  f32x4 acc[4][4] = {};

  auto stage = [&](int buf, int k0) {
    #pragma unroll
    for (int i = 0; i < 4; i++) {
      int s = wave * 4 + i;                 // segment: rows [8s, 8s+8)
      int t = tok[s * 8 + lr];
      gl_lds16(xbf + (size_t)t * D_DIM + k0 + lc, &xs[buf][s * 512]);
    }
    #pragma unroll
    for (int i = 0; i < 4; i++) {
      int s = wave * 4 + i;
      gl_lds16(w1e + (size_t)(s * 8 + lr) * D_DIM + k0 + lc, &bs[buf][s * 512]);
    }
  };

  const int nk = D_DIM / BK;  // 8
  stage(0, 0);
  for (int ki = 0; ki < nk; ki++) {
    __syncthreads();                                       // drains buf[ki&1] loads
    if (ki + 1 < nk) stage((ki + 1) & 1, (ki + 1) * BK);   // fly during compute
    const bf16* xsc = xs[ki & 1];
    const bf16* bsc = bs[ki & 1];
    #pragma unroll
    for (int kk = 0; kk < BK; kk += 32) {
      bf16x8 af[4], bfr[4];
      #pragma unroll
      for (int i = 0; i < 4; i++)
        af[i] = *reinterpret_cast<const bf16x8*>(&xsc[(wm + i * 16 + l16) * BK + kk + quad * 8]);
      #pragma unroll
      for (int j = 0; j < 4; j++)
        bfr[j] = *reinterpret_cast<const bf16x8*>(&bsc[(wn + j * 16 + l16) * BK + kk + quad * 8]);
      #pragma unroll
      for (int i = 0; i < 4; i++)
        #pragma unroll
        for (int j = 0; j < 4; j++)
          acc[i][j] = __builtin_amdgcn_mfma_f32_16x16x32_bf16(af[i], bfr[j], acc[i][j], 0, 0, 0);
    }
  }

  bf16* hrow = hbuf + (size_t)(rbase + m0) * H_DIM;
  #pragma unroll
  for (int i = 0; i < 4; i++) {
    int row = wm + i * 16 + quad * 4;
    #pragma unroll
    for (int j = 0; j < 4; j++) {
      int col = n0 + wn + j * 16 + l16;
      float bias = b1[e * H_DIM + col];
      #pragma unroll
      for (int r = 0; r < 4; r++) {
        float v = acc[i][j][r] + bias;
        v = v > 0.f ? v : 0.f;
        hrow[(size_t)(row + r) * H_DIM + col] = (bf16)v;
      }
    }
  }
}

// ---------------- GEMM2: out += 0.5*(h @ W2 + b2), scattered fp32 atomicAdd ----------------
// single-buffered K-loop (r2 best); same XCD swizzle, NC2 = 4 chunks over D
#define NC2 (D_DIM / BN)   // 4
__global__ __launch_bounds__(256) void gemm2(
    const bf16* __restrict__ hbuf, const bf16* __restrict__ w2t,
    const float* __restrict__ b2, const int* __restrict__ lists,
    const int* __restrict__ cnt, float* __restrict__ out) {
  int lin = blockIdx.x;
  int xcd = lin & 7;
  int rem = lin >> 3;
  int nc  = rem & (NC2 - 1);
  int rb  = (rem >> 2) * 8 + xcd;
  int e   = rb >> 7;
  int m0  = (rb & 127) * BM;
  int ce  = cnt[e];
  if (m0 >= ce) return;
  int n0 = nc * BN;
  int rbase = rowbase_of(cnt, e);

  __shared__ bf16 hs[BM * BK];
  __shared__ bf16 bs[BN * BK];
  __shared__ int tok[BM];

  int tid = threadIdx.x;
  if (tid < BM) {
    int r = m0 + tid;
    tok[tid] = (r < ce) ? lists[e * NTOK + r] : -1;
  }
  __syncthreads();

  const bf16* hbase = hbuf + (size_t)(rbase + m0) * H_DIM;
  const bf16* w2e = w2t + (size_t)e * H_DIM * D_DIM + (size_t)n0 * H_DIM;
  int wave = tid >> 6, lane = tid & 63;
  int quad = lane >> 4, l16 = lane & 15;
  int lr = lane >> 3, lc = (lane & 7) * 8;
  int wm = (wave & 1) * 64, wn = (wave >> 1) * 64;
  f32x4 acc[4][4] = {};

  for (int k0 = 0; k0 < H_DIM; k0 += BK) {
    #pragma unroll
    for (int i = 0; i < 4; i++) {
      int s = wave * 4 + i;
      gl_lds16(hbase + (size_t)(s * 8 + lr) * H_DIM + k0 + lc, &hs[s * 512]);
    }
    #pragma unroll
    for (int i = 0; i < 4; i++) {
      int s = wave * 4 + i;
      gl_lds16(w2e + (size_t)(s * 8 + lr) * H_DIM + k0 + lc, &bs[s * 512]);
    }
    __syncthreads();
    #pragma unroll
    for (int kk = 0; kk < BK; kk += 32) {
      bf16x8 af[4], bfr[4];
      #pragma unroll
      for (int i = 0; i < 4; i++)
        af[i] = *reinterpret_cast<const bf16x8*>(&hs[(wm + i * 16 + l16) * BK + kk + quad * 8]);
      #pragma unroll
      for (int j = 0; j < 4; j++)
        bfr[j] = *reinterpret_cast<const bf16x8*>(&bs[(wn + j * 16 + l16) * BK + kk + quad * 8]);
      #pragma unroll
      for (int i = 0; i < 4; i++)
        #pragma unroll
        for (int j = 0; j < 4; j++)
          acc[i][j] = __builtin_amdgcn_mfma_f32_16x16x32_bf16(af[i], bfr[j], acc[i][j], 0, 0, 0);
    }
    __syncthreads();
  }

  #pragma unroll
  for (int i = 0; i < 4; i++) {
    int row = wm + i * 16 + quad * 4;
    #pragma unroll
    for (int j = 0; j < 4; j++) {
      int col = n0 + wn + j * 16 + l16;
      float bias = b2[e * D_DIM + col];
      #pragma unroll
      for (int r = 0; r < 4; r++) {
        int t = tok[row + r];
        if (t >= 0) {
          float v = 0.5f * (acc[i][j][r] + bias);
          atomicAdd(&out[(size_t)t * D_DIM + col], v);
        }
      }
    }
  }
}

// ---------------- launch ----------------
extern "C" void kernel_launch(void* const* d_in, const int* in_sizes, int n_in,
                              void* d_out, int out_size, void* d_ws, size_t ws_size,
                              hipStream_t stream) {
  const float* x      = (const float*)d_in[0];
  const int*   assign = (const int*)d_in[1];
  const float* W1     = (const float*)d_in[2];
  const float* b1     = (const float*)d_in[3];
  const float* W2     = (const float*)d_in[4];
  const float* b2     = (const float*)d_in[5];
  float* out = (float*)d_out;
  char* ws = (char*)d_ws;

  int* fill    = (int*)(ws + OFF_FILL);
  int* lists   = (int*)(ws + OFF_LIST);
  bf16* xbf    = (bf16*)(ws + OFF_XBF);
  bf16* w1t    = (bf16*)(ws + OFF_W1T);
  bf16* w2t    = (bf16*)(ws + OFF_W2T);
  bf16* hbuf   = (bf16*)(ws + OFF_HBUF);

  hipMemsetAsync(ws, 0, 128, stream);
  hipMemsetAsync(d_out, 0, (size_t)out_size * sizeof(float), stream);

  fill_kernel<<<NTOK / 256, 256, 0, stream>>>(assign, fill, lists);

  cvt_x<<<(NTOK * D_DIM) / (256 * 8), 256, 0, stream>>>(x, xbf);
  // W1 [E][D][H] -> W1T [E][H][D];  W2 [E][H][D] -> W2T [E][D][H]
  transpose_cvt<<<dim3(H_DIM / 32, D_DIM / 32, E_NUM), dim3(32, 8), 0, stream>>>(W1, w1t, D_DIM, H_DIM);
  transpose_cvt<<<dim3(D_DIM / 32, H_DIM / 32, E_NUM), dim3(32, 8), 0, stream>>>(W2, w2t, H_DIM, D_DIM);

  // 1D swizzled grids: total = (E*NTOK/BM) * NC, encode lin = xcd + 8*(nc + NC*rbHi)
  gemm1<<<(E_NUM * NTOK / BM) * NC1, 256, 0, stream>>>(xbf, w1t, b1, lists, fill, hbuf);
  gemm2<<<(E_NUM * NTOK / BM) * NC2, 256, 0, stream>>>(hbuf, w2t, b2, lists, fill, out);

  (void)in_sizes; (void)n_in; (void)ws_size;
}